// Round 1
// baseline (2767.771 us; speedup 1.0000x reference)
//
#include <hip/hip_runtime.h>
#include <hip/hip_bf16.h>

#define D_ 512
#define S_ 1024
#define B_ 8
#define V_ 32000
#define M_ 8192   // B_*S_

typedef __bf16 bf16x8 __attribute__((ext_vector_type(8)));
typedef float f32x4 __attribute__((ext_vector_type(4)));

__device__ __forceinline__ float sigf(float x) { return 1.0f / (1.0f + __expf(-x)); }

// ---------------------------------------------------------------------------
// K1: embedding gather + 3 fp32 GEMMs.  z=0: f = sigmoid(emb@Wih + bh)
//                                       z=1: x = silu(emb@W1+b1) * (emb@W2+b2)
// BM=128, BN=64, BK=16, 256 threads, 8x4 micro-tile.
// ---------------------------------------------------------------------------
__global__ __launch_bounds__(256) void k1_fx(
    const int* __restrict__ tok, const float* __restrict__ E,
    const float* __restrict__ Wih, const float* __restrict__ bh,
    const float* __restrict__ W1, const float* __restrict__ b1v,
    const float* __restrict__ W2, const float* __restrict__ b2v,
    float* __restrict__ fO, float* __restrict__ xO)
{
    __shared__ float As[16][128];   // transposed A tile
    __shared__ float Bs0[16][64];
    __shared__ float Bs1[16][64];
    __shared__ int toks[128];
    const int tid = threadIdx.x;
    const int zi = blockIdx.z;
    const int m0 = blockIdx.x * 128;
    const int n0 = blockIdx.y * 64;
    if (tid < 128) toks[tid] = tok[m0 + tid];
    __syncthreads();
    const int ty = tid >> 4, tx = tid & 15;
    const int ar0 = tid >> 2, ak = (tid & 3) * 4;  // A stage: rows 0..63
    const int ar1 = ar0 + 64;                      // rows 64..127
    const int bk = tid >> 4, bn = (tid & 15) * 4;
    const float* WA = zi ? W1 : Wih;
    float acc0[8][4] = {};
    float acc1[8][4] = {};
    for (int k0 = 0; k0 < D_; k0 += 16) {
        float4 a0 = *(const float4*)(E + (size_t)toks[ar0] * D_ + k0 + ak);
        float4 a1 = *(const float4*)(E + (size_t)toks[ar1] * D_ + k0 + ak);
        float4 bv0 = *(const float4*)(WA + (size_t)(k0 + bk) * D_ + n0 + bn);
        float4 bv1 = make_float4(0.f, 0.f, 0.f, 0.f);
        if (zi) bv1 = *(const float4*)(W2 + (size_t)(k0 + bk) * D_ + n0 + bn);
        __syncthreads();
        As[ak + 0][ar0] = a0.x; As[ak + 1][ar0] = a0.y; As[ak + 2][ar0] = a0.z; As[ak + 3][ar0] = a0.w;
        As[ak + 0][ar1] = a1.x; As[ak + 1][ar1] = a1.y; As[ak + 2][ar1] = a1.z; As[ak + 3][ar1] = a1.w;
        *(float4*)&Bs0[bk][bn] = bv0;
        if (zi) *(float4*)&Bs1[bk][bn] = bv1;
        __syncthreads();
        #pragma unroll
        for (int k = 0; k < 16; ++k) {
            float4 av0 = *(const float4*)&As[k][ty * 8];
            float4 av1 = *(const float4*)&As[k][ty * 8 + 4];
            float4 bq0 = *(const float4*)&Bs0[k][tx * 4];
            float a[8] = {av0.x, av0.y, av0.z, av0.w, av1.x, av1.y, av1.z, av1.w};
            float bb[4] = {bq0.x, bq0.y, bq0.z, bq0.w};
            #pragma unroll
            for (int i = 0; i < 8; ++i)
                #pragma unroll
                for (int j = 0; j < 4; ++j)
                    acc0[i][j] += a[i] * bb[j];
            if (zi) {
                float4 bq1 = *(const float4*)&Bs1[k][tx * 4];
                float bc[4] = {bq1.x, bq1.y, bq1.z, bq1.w};
                #pragma unroll
                for (int i = 0; i < 8; ++i)
                    #pragma unroll
                    for (int j = 0; j < 4; ++j)
                        acc1[i][j] += a[i] * bc[j];
            }
        }
    }
    #pragma unroll
    for (int i = 0; i < 8; ++i) {
        const int r = m0 + ty * 8 + i;
        #pragma unroll
        for (int j = 0; j < 4; ++j) {
            const int c = n0 + tx * 4 + j;
            if (zi == 0) {
                fO[(size_t)r * D_ + c] = sigf(acc0[i][j] + bh[c]);
            } else {
                float u1 = acc0[i][j] + b1v[c];
                float u2 = acc1[i][j] + b2v[c];
                xO[(size_t)r * D_ + c] = u1 * sigf(u1) * u2;
            }
        }
    }
}

// ---------------------------------------------------------------------------
// K2: blocks 0..7: the sequential scan (one wave per batch), per-step LN via
// shuffle butterfly, final LN fused -> bf16 xf.  Blocks 8..: E fp32->bf16.
// ---------------------------------------------------------------------------
__global__ __launch_bounds__(64) void k2_scan(
    const float* __restrict__ gF, const float* __restrict__ gX,
    const float* __restrict__ lnG, const float* __restrict__ lnB,
    const float* __restrict__ h0p,
    const float* __restrict__ lfG, const float* __restrict__ lfB,
    const float* __restrict__ Ein,
    __hip_bfloat16* __restrict__ xfO, __hip_bfloat16* __restrict__ EbO)
{
    const int blk = blockIdx.x;
    const int lane = threadIdx.x;
    if (blk >= B_) {
        // E conversion: 16000 blocks x 256 float4 = 16.384M floats
        const float4* E4 = (const float4*)Ein;
        uint2* O2 = (uint2*)EbO;
        const size_t base = (size_t)(blk - B_) * 256;
        #pragma unroll
        for (int it = 0; it < 4; ++it) {
            size_t i4 = base + it * 64 + lane;
            float4 v = E4[i4];
            union { __hip_bfloat16 h[4]; uint2 u; } pk;
            pk.h[0] = __float2bfloat16(v.x); pk.h[1] = __float2bfloat16(v.y);
            pk.h[2] = __float2bfloat16(v.z); pk.h[3] = __float2bfloat16(v.w);
            O2[i4] = pk.u;
        }
        return;
    }
    const int dA = lane * 4;
    const int dB2 = 256 + lane * 4;
    float h[8], lg[8], lb[8], fg[8], fb[8];
    {
        float4 t0 = *(const float4*)(h0p + dA), t1 = *(const float4*)(h0p + dB2);
        h[0]=t0.x; h[1]=t0.y; h[2]=t0.z; h[3]=t0.w; h[4]=t1.x; h[5]=t1.y; h[6]=t1.z; h[7]=t1.w;
        t0 = *(const float4*)(lnG + dA); t1 = *(const float4*)(lnG + dB2);
        lg[0]=t0.x; lg[1]=t0.y; lg[2]=t0.z; lg[3]=t0.w; lg[4]=t1.x; lg[5]=t1.y; lg[6]=t1.z; lg[7]=t1.w;
        t0 = *(const float4*)(lnB + dA); t1 = *(const float4*)(lnB + dB2);
        lb[0]=t0.x; lb[1]=t0.y; lb[2]=t0.z; lb[3]=t0.w; lb[4]=t1.x; lb[5]=t1.y; lb[6]=t1.z; lb[7]=t1.w;
        t0 = *(const float4*)(lfG + dA); t1 = *(const float4*)(lfG + dB2);
        fg[0]=t0.x; fg[1]=t0.y; fg[2]=t0.z; fg[3]=t0.w; fg[4]=t1.x; fg[5]=t1.y; fg[6]=t1.z; fg[7]=t1.w;
        t0 = *(const float4*)(lfB + dA); t1 = *(const float4*)(lfB + dB2);
        fb[0]=t0.x; fb[1]=t0.y; fb[2]=t0.z; fb[3]=t0.w; fb[4]=t1.x; fb[5]=t1.y; fb[6]=t1.z; fb[7]=t1.w;
    }
    const float* fp = gF + (size_t)blk * S_ * D_;
    const float* xp = gX + (size_t)blk * S_ * D_;
    __hip_bfloat16* op = xfO + (size_t)blk * S_ * D_;
    float4 cf0 = *(const float4*)(fp + dA);
    float4 cf1 = *(const float4*)(fp + dB2);
    float4 cx0 = *(const float4*)(xp + dA);
    float4 cx1 = *(const float4*)(xp + dB2);
    float4 nf0 = *(const float4*)(fp + D_ + dA);
    float4 nf1 = *(const float4*)(fp + D_ + dB2);
    float4 nx0 = *(const float4*)(xp + D_ + dA);
    float4 nx1 = *(const float4*)(xp + D_ + dB2);
    for (int t = 0; t < S_; ++t) {
        float4 tf0 = cf0, tf1 = cf1, tx0 = cx0, tx1 = cx1;
        if (t + 2 < S_) {
            const float* fq = fp + (size_t)(t + 2) * D_;
            const float* xq = xp + (size_t)(t + 2) * D_;
            tf0 = *(const float4*)(fq + dA);
            tf1 = *(const float4*)(fq + dB2);
            tx0 = *(const float4*)(xq + dA);
            tx1 = *(const float4*)(xq + dB2);
        }
        float fv[8] = {cf0.x, cf0.y, cf0.z, cf0.w, cf1.x, cf1.y, cf1.z, cf1.w};
        float xv[8] = {cx0.x, cx0.y, cx0.z, cx0.w, cx1.x, cx1.y, cx1.z, cx1.w};
        float hr[8];
        float s = 0.f, q = 0.f;
        #pragma unroll
        for (int j = 0; j < 8; ++j) {
            hr[j] = fv[j] * (h[j] - xv[j]) + xv[j];  // f*h + (1-f)*x
            s += hr[j];
            q += hr[j] * hr[j];
        }
        #pragma unroll
        for (int mk = 32; mk >= 1; mk >>= 1) {
            s += __shfl_xor(s, mk, 64);
            q += __shfl_xor(q, mk, 64);
        }
        const float mean = s * (1.0f / 512.0f);
        const float var = q * (1.0f / 512.0f) - mean * mean;
        const float rs = rsqrtf(var + 1e-5f);
        float s2 = 0.f, q2 = 0.f;
        #pragma unroll
        for (int j = 0; j < 8; ++j) {
            float hn = (hr[j] - mean) * rs * lg[j] + lb[j] + h[j];
            h[j] = hn;
            s2 += hn;
            q2 += hn * hn;
        }
        #pragma unroll
        for (int mk = 32; mk >= 1; mk >>= 1) {
            s2 += __shfl_xor(s2, mk, 64);
            q2 += __shfl_xor(q2, mk, 64);
        }
        const float m2 = s2 * (1.0f / 512.0f);
        const float rs2 = rsqrtf(q2 * (1.0f / 512.0f) - m2 * m2 + 1e-5f);
        union { __hip_bfloat16 hh[4]; uint2 u; } p0, p1;
        #pragma unroll
        for (int j = 0; j < 4; ++j) p0.hh[j] = __float2bfloat16((h[j] - m2) * rs2 * fg[j] + fb[j]);
        #pragma unroll
        for (int j = 0; j < 4; ++j) p1.hh[j] = __float2bfloat16((h[4 + j] - m2) * rs2 * fg[4 + j] + fb[4 + j]);
        __hip_bfloat16* orow = op + (size_t)t * D_;
        *(uint2*)(orow + dA) = p0.u;
        *(uint2*)(orow + dB2) = p1.u;
        cf0 = nf0; cf1 = nf1; cx0 = nx0; cx1 = nx1;
        nf0 = tf0; nf1 = tf1; nx0 = tx0; nx1 = tx1;
    }
}

// ---------------------------------------------------------------------------
// K4: logits = xf[8192,512] @ E^T  (NT GEMM), bf16 MFMA 16x16x32, 128x128 tile,
// BK=32, 4 waves each 64x64, global_load_lds width-16 staging (m97 structure).
// EB=true: B already bf16 in ws; EB=false: convert fp32 E in-tile.
// ---------------------------------------------------------------------------
template <bool EB>
__global__ __launch_bounds__(256) void k4_logits(
    const __hip_bfloat16* __restrict__ A,
    const __hip_bfloat16* __restrict__ Bb,
    const float* __restrict__ Bf,
    float* __restrict__ C)
{
    __shared__ __hip_bfloat16 sA[128 * 32];
    __shared__ __hip_bfloat16 sB[128 * 32];
    const int tid = threadIdx.x;
    const int wave = tid >> 6;
    const int lane = tid & 63;
    const int n0 = blockIdx.x * 128;
    const int m0 = blockIdx.y * 128;
    const int wm = (wave >> 1) * 64;
    const int wn = (wave & 1) * 64;
    const int c0 = wave * 128 + lane;
    const int c1 = c0 + 64;
    const int r0 = c0 >> 2, kc0 = (c0 & 3) * 8;
    const int r1 = c1 >> 2, kc1 = (c1 & 3) * 8;
    const int fr = lane & 15;
    const int kq = (lane >> 4) * 8;
    f32x4 acc[4][4] = {};
    for (int k0 = 0; k0 < D_; k0 += 32) {
        __syncthreads();
        __builtin_amdgcn_global_load_lds(
            (const __attribute__((address_space(1))) void*)(A + (size_t)(m0 + r0) * D_ + k0 + kc0),
            (__attribute__((address_space(3))) void*)(sA + wave * 1024), 16, 0, 0);
        __builtin_amdgcn_global_load_lds(
            (const __attribute__((address_space(1))) void*)(A + (size_t)(m0 + r1) * D_ + k0 + kc1),
            (__attribute__((address_space(3))) void*)(sA + wave * 1024 + 512), 16, 0, 0);
        if (EB) {
            __builtin_amdgcn_global_load_lds(
                (const __attribute__((address_space(1))) void*)(Bb + (size_t)(n0 + r0) * D_ + k0 + kc0),
                (__attribute__((address_space(3))) void*)(sB + wave * 1024), 16, 0, 0);
            __builtin_amdgcn_global_load_lds(
                (const __attribute__((address_space(1))) void*)(Bb + (size_t)(n0 + r1) * D_ + k0 + kc1),
                (__attribute__((address_space(3))) void*)(sB + wave * 1024 + 512), 16, 0, 0);
        } else {
            #pragma unroll
            for (int jj = 0; jj < 2; ++jj) {
                const int c = (jj == 0) ? c0 : c1;
                const int rr = c >> 2, kk = (c & 3) * 8;
                const float* gb = Bf + (size_t)(n0 + rr) * D_ + k0 + kk;
                float4 v0 = *(const float4*)gb;
                float4 v1 = *(const float4*)(gb + 4);
                union { __hip_bfloat16 hh[8]; uint4 u; } pk;
                pk.hh[0] = __float2bfloat16(v0.x); pk.hh[1] = __float2bfloat16(v0.y);
                pk.hh[2] = __float2bfloat16(v0.z); pk.hh[3] = __float2bfloat16(v0.w);
                pk.hh[4] = __float2bfloat16(v1.x); pk.hh[5] = __float2bfloat16(v1.y);
                pk.hh[6] = __float2bfloat16(v1.z); pk.hh[7] = __float2bfloat16(v1.w);
                *(uint4*)(sB + c * 8) = pk.u;
            }
        }
        __syncthreads();
        bf16x8 fa[4], fbr[4];
        #pragma unroll
        for (int i = 0; i < 4; ++i) {
            fa[i]  = *(const bf16x8*)(sA + (wm + i * 16 + fr) * 32 + kq);
            fbr[i] = *(const bf16x8*)(sB + (wn + i * 16 + fr) * 32 + kq);
        }
        #pragma unroll
        for (int i = 0; i < 4; ++i)
            #pragma unroll
            for (int j = 0; j < 4; ++j)
                acc[i][j] = __builtin_amdgcn_mfma_f32_16x16x32_bf16(fa[i], fbr[j], acc[i][j], 0, 0, 0);
    }
    const int cm = (lane >> 4) * 4;
    const int cn = lane & 15;
    #pragma unroll
    for (int i = 0; i < 4; ++i)
        #pragma unroll
        for (int j = 0; j < 4; ++j) {
            float* cp = C + (size_t)(m0 + wm + i * 16 + cm) * V_ + (n0 + wn + j * 16 + cn);
            #pragma unroll
            for (int r = 0; r < 4; ++r)
                cp[(size_t)r * V_] = acc[i][j][r];
        }
}

// ---------------------------------------------------------------------------
extern "C" void kernel_launch(void* const* d_in, const int* in_sizes, int n_in,
                              void* d_out, int out_size, void* d_ws, size_t ws_size,
                              hipStream_t stream)
{
    (void)in_sizes; (void)n_in; (void)out_size;
    const int* tok = (const int*)d_in[0];
    const float* E = (const float*)d_in[1];
    const float* Wih = (const float*)d_in[2];
    const float* bh = (const float*)d_in[3];
    const float* W1 = (const float*)d_in[4];
    const float* b1 = (const float*)d_in[5];
    const float* W2 = (const float*)d_in[6];
    const float* b2 = (const float*)d_in[7];
    const float* lng = (const float*)d_in[8];
    const float* lnb = (const float*)d_in[9];
    const float* h0 = (const float*)d_in[10];
    const float* lfg = (const float*)d_in[11];
    const float* lfb = (const float*)d_in[12];
    float* out = (float*)d_out;

    // ws layout (tier A): f[M,D] f32 | x[M,D] f32 | xf[M,D] bf16 | Eb[V,D] bf16
    const size_t needA = (size_t)M_ * D_ * 10 + (size_t)V_ * D_ * 2;  // 74.7 MB
    const bool tierA = ws_size >= needA;

    float *fB, *xB;
    __hip_bfloat16 *xf, *Eb;
    if (tierA) {
        fB = (float*)d_ws;
        xB = fB + (size_t)M_ * D_;
        xf = (__hip_bfloat16*)(xB + (size_t)M_ * D_);
        Eb = xf + (size_t)M_ * D_;
    } else {
        // stash f/x in the dead tail of d_out (overwritten only by k4 at the end)
        const size_t out_bytes = (size_t)M_ * V_ * 4;               // 1,048,576,000
        const size_t fx_bytes = (size_t)M_ * D_ * 8;                // 33,554,432
        fB = (float*)((char*)d_out + (out_bytes - fx_bytes));
        xB = fB + (size_t)M_ * D_;
        xf = (__hip_bfloat16*)d_ws;                                 // needs 8.4 MB
        Eb = nullptr;
    }

    k1_fx<<<dim3(64, 8, 2), 256, 0, stream>>>(tok, E, Wih, bh, W1, b1, W2, b2, fB, xB);
    if (tierA) {
        k2_scan<<<dim3(B_ + 16000), 64, 0, stream>>>(fB, xB, lng, lnb, h0, lfg, lfb, E, xf, Eb);
        k4_logits<true><<<dim3(250, 64), 256, 0, stream>>>(xf, Eb, nullptr, out);
    } else {
        k2_scan<<<dim3(B_), 64, 0, stream>>>(fB, xB, lng, lnb, h0, lfg, lfb, E, xf, nullptr);
        k4_logits<false><<<dim3(250, 64), 256, 0, stream>>>(xf, nullptr, E, out);
    }
}